// Round 1
// baseline (1076.791 us; speedup 1.0000x reference)
//
#include <hip/hip_runtime.h>
#include <hip/hip_bf16.h>
#include <hip/hip_fp16.h>
#include <math.h>

#define B_ 4
#define N_ 2048
#define D_ 512

typedef __bf16    bf16x8  __attribute__((ext_vector_type(8)));
typedef float     floatx4 __attribute__((ext_vector_type(4)));
typedef _Float16  half8   __attribute__((ext_vector_type(8)));

// ---------------------------------------------------------------------------
// async global->LDS, 16B per lane, wave-uniform LDS base (HW adds lane*16)
// ---------------------------------------------------------------------------
__device__ __forceinline__ void gload16(const void* g, void* l) {
  __builtin_amdgcn_global_load_lds(
      (const __attribute__((address_space(1))) void*)g,
      (__attribute__((address_space(3))) void*)l, 16, 0, 0);
}

// ---------------------------------------------------------------------------
// L2-normalize rows of (rows, 512) f32 -> bf16
// ---------------------------------------------------------------------------
__global__ __launch_bounds__(256) void norm_kernel(const float* __restrict__ in,
                                                   __hip_bfloat16* __restrict__ out) {
  const size_t row = blockIdx.x;
  const int t = threadIdx.x;
  const float* src = in + row * D_;
  float v0 = src[t], v1 = src[t + 256];
  float ss = fmaf(v0, v0, v1 * v1);
#pragma unroll
  for (int off = 1; off < 64; off <<= 1) ss += __shfl_xor(ss, off);
  __shared__ float red[4];
  if ((t & 63) == 0) red[t >> 6] = ss;
  __syncthreads();
  const float tot = red[0] + red[1] + red[2] + red[3];
  const float scale = 1.0f / fmaxf(sqrtf(tot), 1e-12f);
  out[row * D_ + t]       = __float2bfloat16(v0 * scale);
  out[row * D_ + t + 256] = __float2bfloat16(v1 * scale);
}

// ---------------------------------------------------------------------------
// Batched NT GEMM: G[b][n][m] = sum_k A[b][n][k] * Bm[b][m][k]   (bf16 -> fp16)
// 128x128 tile, BK=32, 4 waves (2x2 of 64x64), 16x16x32 MFMA, global_load_lds
// ---------------------------------------------------------------------------
__global__ __launch_bounds__(256) void gram_gemm(const __hip_bfloat16* __restrict__ A,
                                                 const __hip_bfloat16* __restrict__ Bm,
                                                 __half* __restrict__ G) {
  __shared__ __hip_bfloat16 As[128 * 32];
  __shared__ __hip_bfloat16 Bs[128 * 32];
  const int t = threadIdx.x;
  const int wave = t >> 6, lane = t & 63;
  const int bm0 = blockIdx.x * 128, bn0 = blockIdx.y * 128;
  const size_t bb = blockIdx.z;
  const __hip_bfloat16* Ab = A  + bb * (size_t)(N_ * D_);
  const __hip_bfloat16* Bb = Bm + bb * (size_t)(N_ * D_);
  floatx4 acc[4][4] = {};
  const int wr = wave >> 1, wc = wave & 1;
  const int srow = t >> 2;          // 0..63 staging row
  const int scol = (t & 3) * 8;     // bf16 col offset (16B chunks)
  char* AsB = (char*)As;
  char* BsB = (char*)Bs;
  const int ldsOff = wave * 1024;   // wave-uniform byte offset within a 4KB round

  for (int k0 = 0; k0 < D_; k0 += 32) {
    __syncthreads();
    gload16(Ab + (size_t)(bm0 + srow)      * D_ + k0 + scol, AsB + ldsOff);
    gload16(Ab + (size_t)(bm0 + 64 + srow) * D_ + k0 + scol, AsB + 4096 + ldsOff);
    gload16(Bb + (size_t)(bn0 + srow)      * D_ + k0 + scol, BsB + ldsOff);
    gload16(Bb + (size_t)(bn0 + 64 + srow) * D_ + k0 + scol, BsB + 4096 + ldsOff);
    __syncthreads();

    const int lrow = lane & 15, lk = (lane >> 4) * 8;
    bf16x8 af[4], bfr[4];
#pragma unroll
    for (int mi = 0; mi < 4; ++mi)
      af[mi] = *(const bf16x8*)((const char*)As + ((wr * 64 + mi * 16 + lrow) * 32 + lk) * 2);
#pragma unroll
    for (int ni = 0; ni < 4; ++ni)
      bfr[ni] = *(const bf16x8*)((const char*)Bs + ((wc * 64 + ni * 16 + lrow) * 32 + lk) * 2);
#pragma unroll
    for (int mi = 0; mi < 4; ++mi)
#pragma unroll
      for (int ni = 0; ni < 4; ++ni)
        acc[mi][ni] = __builtin_amdgcn_mfma_f32_16x16x32_bf16(af[mi], bfr[ni], acc[mi][ni], 0, 0, 0);
  }

  __half* Gb = G + bb * (size_t)N_ * N_;
  const int orow = (lane >> 4) * 4, ocol = lane & 15;
#pragma unroll
  for (int mi = 0; mi < 4; ++mi)
#pragma unroll
    for (int ni = 0; ni < 4; ++ni) {
      const int row = bm0 + wr * 64 + mi * 16 + orow;
      const int col = bn0 + wc * 64 + ni * 16 + ocol;
#pragma unroll
      for (int r = 0; r < 4; ++r)
        Gb[(size_t)(row + r) * N_ + col] = __float2half(acc[mi][ni][r]);
    }
}

// ---------------------------------------------------------------------------
// Softmin pass over all four matrices.
//   out[n] = -eps * lse_m( hbase + potH[m]/eps + G[n][m]/eps ),  hbase = -log(2048) - 1/eps
// MODE 0: init (h = log_w only), write pot directly
// MODE 1: update, write 0.5*(old + v)
// MODE 2: final, accumulate signed weighted sums into *out
// Grid: 1024 blocks of 256 (4 mats x 4 batches x 64 blocks x 32 rows)
// ---------------------------------------------------------------------------
template <int MODE>
__global__ __launch_bounds__(256) void softmin_kernel(
    const __half* __restrict__ Gxy, const __half* __restrict__ Gyx,
    const __half* __restrict__ Gxx, const __half* __restrict__ Gyy,
    const float* __restrict__ potOld, float* __restrict__ potNew,
    float eps, float* __restrict__ out) {
  const int bid = blockIdx.x;
  const int mat = bid >> 8;
  const int rem = bid & 255;
  const int b   = rem >> 6;
  const int rb  = (rem & 63) * 32;
  const int lane = threadIdx.x & 63, wave = threadIdx.x >> 6;

  const __half* G = (mat == 0 ? Gxy : mat == 1 ? Gyx : mat == 2 ? Gxx : Gyy)
                    + (size_t)b * N_ * N_;
  const int hsel = (mat == 0) ? 1 : (mat == 1) ? 0 : mat;
  const float* potH = potOld + ((size_t)hsel * B_ + b) * N_;
  const float* potO = potOld + ((size_t)mat  * B_ + b) * N_;
  float*       potW = potNew + ((size_t)mat  * B_ + b) * N_;

  const float inv_eps = 1.0f / eps;
  const float hbase = -7.62461898616f - inv_eps;   // -log(2048) - 1/eps

  float hh[32];
  if constexpr (MODE != 0) {
#pragma unroll
    for (int p = 0; p < 4; ++p) {
      const float4 a = *(const float4*)(potH + p * 512 + lane * 8);
      const float4 c = *(const float4*)(potH + p * 512 + lane * 8 + 4);
      hh[p * 8 + 0] = fmaf(a.x, inv_eps, hbase);
      hh[p * 8 + 1] = fmaf(a.y, inv_eps, hbase);
      hh[p * 8 + 2] = fmaf(a.z, inv_eps, hbase);
      hh[p * 8 + 3] = fmaf(a.w, inv_eps, hbase);
      hh[p * 8 + 4] = fmaf(c.x, inv_eps, hbase);
      hh[p * 8 + 5] = fmaf(c.y, inv_eps, hbase);
      hh[p * 8 + 6] = fmaf(c.z, inv_eps, hbase);
      hh[p * 8 + 7] = fmaf(c.w, inv_eps, hbase);
    }
  } else {
#pragma unroll
    for (int j = 0; j < 32; ++j) hh[j] = hbase;
  }

  float lsum = 0.0f;

#pragma unroll 1
  for (int it = 0; it < 4; ++it) {
    const int r0 = rb + wave * 8 + it * 2;
    const __half* g0 = G + (size_t)r0 * N_;
    const __half* g1 = g0 + N_;

    half8 a0[4], a1[4];
#pragma unroll
    for (int p = 0; p < 4; ++p) {
      const int m0 = p * 512 + lane * 8;
      a0[p] = *(const half8*)(g0 + m0);
      a1[p] = *(const half8*)(g1 + m0);
    }

    float mx0 = -3.0e38f, mx1 = -3.0e38f;
#pragma unroll
    for (int p = 0; p < 4; ++p)
#pragma unroll
      for (int e = 0; e < 8; ++e) {
        const float t0 = fmaf((float)a0[p][e], inv_eps, hh[p * 8 + e]);
        const float t1 = fmaf((float)a1[p][e], inv_eps, hh[p * 8 + e]);
        mx0 = fmaxf(mx0, t0);
        mx1 = fmaxf(mx1, t1);
      }
#pragma unroll
    for (int off = 1; off < 64; off <<= 1) {
      mx0 = fmaxf(mx0, __shfl_xor(mx0, off));
      mx1 = fmaxf(mx1, __shfl_xor(mx1, off));
    }

    float sm0 = 0.0f, sm1 = 0.0f;
#pragma unroll
    for (int p = 0; p < 4; ++p)
#pragma unroll
      for (int e = 0; e < 8; ++e) {
        const float t0 = fmaf((float)a0[p][e], inv_eps, hh[p * 8 + e]);
        const float t1 = fmaf((float)a1[p][e], inv_eps, hh[p * 8 + e]);
        sm0 += __expf(t0 - mx0);
        sm1 += __expf(t1 - mx1);
      }
#pragma unroll
    for (int off = 1; off < 64; off <<= 1) {
      sm0 += __shfl_xor(sm0, off);
      sm1 += __shfl_xor(sm1, off);
    }

    const float v0 = -eps * (mx0 + __logf(sm0));
    const float v1 = -eps * (mx1 + __logf(sm1));

    if constexpr (MODE == 2) {
      lsum += v0 + v1;
    } else if constexpr (MODE == 1) {
      if (lane == 0) {
        potW[r0]     = 0.5f * (potO[r0]     + v0);
        potW[r0 + 1] = 0.5f * (potO[r0 + 1] + v1);
      }
    } else {
      if (lane == 0) {
        potW[r0]     = v0;
        potW[r0 + 1] = v1;
      }
    }
  }

  if constexpr (MODE == 2) {
    __shared__ float red[4];
    if (lane == 0) red[wave] = lsum;
    __syncthreads();
    if (threadIdx.x == 0) {
      const float sign = (mat < 2) ? 1.0f : -1.0f;
      atomicAdd(out, sign * (red[0] + red[1] + red[2] + red[3]) * (1.0f / (2048.0f * B_)));
    }
  }
}

// ---------------------------------------------------------------------------
extern "C" void kernel_launch(void* const* d_in, const int* in_sizes, int n_in,
                              void* d_out, int out_size, void* d_ws, size_t ws_size,
                              hipStream_t stream) {
  const float* E_p = (const float*)d_in[0];
  const float* E_t = (const float*)d_in[1];
  float* out = (float*)d_out;
  char* ws = (char*)d_ws;

  size_t off = 0;
  auto alloc = [&](size_t bytes) {
    void* p = ws + off;
    off += (bytes + 255) & ~(size_t)255;
    return p;
  };
  __hip_bfloat16* Xb = (__hip_bfloat16*)alloc((size_t)B_ * N_ * D_ * 2);
  __hip_bfloat16* Yb = (__hip_bfloat16*)alloc((size_t)B_ * N_ * D_ * 2);
  __half* Gxy = (__half*)alloc((size_t)B_ * N_ * N_ * 2);
  __half* Gyx = (__half*)alloc((size_t)B_ * N_ * N_ * 2);
  __half* Gxx = (__half*)alloc((size_t)B_ * N_ * N_ * 2);
  __half* Gyy = (__half*)alloc((size_t)B_ * N_ * N_ * 2);
  float* potA = (float*)alloc((size_t)4 * B_ * N_ * 4);
  float* potB = (float*)alloc((size_t)4 * B_ * N_ * 4);

  // normalize
  norm_kernel<<<B_ * N_, 256, 0, stream>>>(E_p, Xb);
  norm_kernel<<<B_ * N_, 256, 0, stream>>>(E_t, Yb);

  // Gram matrices
  dim3 gg(16, 16, B_);
  gram_gemm<<<gg, 256, 0, stream>>>(Xb, Yb, Gxy);
  gram_gemm<<<gg, 256, 0, stream>>>(Yb, Xb, Gyx);
  gram_gemm<<<gg, 256, 0, stream>>>(Xb, Xb, Gxx);
  gram_gemm<<<gg, 256, 0, stream>>>(Yb, Yb, Gyy);

  // epsilon schedule (replicates numpy arange semantics in double)
  float epsl[48];
  int ne = 0;
  epsl[ne++] = 4.0f;
  {
    const double lstart = 2.0 * log(2.0);
    const double lstop  = 2.0 * log(0.05);
    const double lstep  = 2.0 * log(0.9);
    for (int k = 0;; ++k) {
      const double v = lstart + k * lstep;
      if (!(v > lstop)) break;
      epsl[ne++] = (float)exp(v);
    }
  }
  epsl[ne++] = 0.0025f;   // blur^2

  // init at eps0
  softmin_kernel<0><<<1024, 256, 0, stream>>>(Gxy, Gyx, Gxx, Gyy, potA, potA, epsl[0], nullptr);

  // scan over the full schedule
  float* cur = potA;
  float* nxt = potB;
  for (int i = 0; i < ne; ++i) {
    softmin_kernel<1><<<1024, 256, 0, stream>>>(Gxy, Gyx, Gxx, Gyy, cur, nxt, epsl[i], nullptr);
    float* tmp = cur; cur = nxt; nxt = tmp;
  }

  // final extrapolation + loss reduction
  hipMemsetAsync(d_out, 0, sizeof(float), stream);
  softmin_kernel<2><<<1024, 256, 0, stream>>>(Gxy, Gyx, Gxx, Gyy, cur, cur, epsl[ne - 1], out);
}